// Round 4
// baseline (85.480 us; speedup 1.0000x reference)
//
#include <hip/hip_runtime.h>
#include <hip/hip_bf16.h>

// Problem constants (B, T, C, HS) from the reference.
#define NB 256
#define NT 256
#define NC 384
#define NH 64
#define NQ (NB * NT * NH)   // elements per q/k/v tensor = 4194304
#define NW 192              // 3 * NH concatenated output cols
#define WT_ELEMS (NW * NC)  // Wt bf16 elements = 73728

typedef short bf16x8 __attribute__((ext_vector_type(8)));
typedef float f32x4 __attribute__((ext_vector_type(4)));

__device__ __forceinline__ float bf2f(unsigned short u) {
  union { unsigned int i; float f; } c;
  c.i = ((unsigned int)u) << 16;
  return c.f;
}

__device__ __forceinline__ unsigned short f2bf(float f) {
  union { float f; unsigned int i; } c;
  c.f = f;
  const unsigned int r = c.i + 0x7fffu + ((c.i >> 16) & 1u);
  return (unsigned short)(r >> 16);
}

// HW bf16 convert (compiler emits v_cvt_pk_bf16_f32 for fused pairs).
__device__ __forceinline__ unsigned short f2bf_hw(float f) {
  __hip_bfloat16 b = __float2bfloat16(f);
  return *reinterpret_cast<unsigned short*>(&b);
}

// ---------------------------------------------------------------------------
// Kernel 0: transpose + convert weights.
// Wt[n][k] (bf16, [192][384]) = W{q,k,v}[k][n%64].
// ---------------------------------------------------------------------------
__global__ __launch_bounds__(256) void w_transpose_kernel(
    const float* __restrict__ Wq,
    const float* __restrict__ Wk,
    const float* __restrict__ Wv,
    unsigned short* __restrict__ Wt) {
  const int idx = blockIdx.x * 256 + threadIdx.x;
  if (idx >= WT_ELEMS) return;
  const int n = idx / NC, k = idx - n * NC;
  const float* W = (n < 64) ? Wq : (n < 128) ? Wk : Wv;
  Wt[idx] = f2bf(W[k * NH + (n & 63)]);
}

// ---------------------------------------------------------------------------
// Kernel 1: fused QKV projection via MFMA, round-4 structure.
//   [65536 x 384] (x, fp32->bf16 inline) @ [384 x 192] (Wt) -> qkv bf16.
// Block = 256 thr = 4 waves arranged 2x2: wave (wr,wc) owns rows wr*32..+32,
// cols wc*96..+96. Block tile = 64 rows x 192 cols; grid = 1024 blocks
// (4 blocks/CU, 16 waves/CU with __launch_bounds__(256,4)).
// acc = 2x6 f32x4 = 48 VGPR/lane.
// Epilogue: acc -> padded LDS tile [64][208] (stride 208 shorts = 104 words
// == 8 banks mod 32 -> the four lg row-groups hit disjoint bank octets,
// conflict-free), then coalesced uint4 (16B) global stores.
// mfma_f32_16x16x32_bf16 layouts (HW-verified round 2):
//   A/B: k = (l>>4)*8+j contiguous;  D: n = l&15, m = (l>>4)*4 + r.
// ---------------------------------------------------------------------------
#define SROW 208  // padded LDS row stride in shorts
__global__ __launch_bounds__(256, 4) void qkv_proj_mfma(
    const float* __restrict__ x,
    const unsigned short* __restrict__ Wt,
    unsigned short* __restrict__ qkv) {
  __shared__ unsigned short Sls[64 * SROW];  // 26.6 KB

  const int tid = threadIdx.x;
  const int w = tid >> 6;
  const int lane = tid & 63;
  const int l15 = lane & 15;
  const int lg = lane >> 4;
  const int wr = w >> 1;     // row half 0..1
  const int wc = w & 1;      // col half 0..1
  const int row0 = blockIdx.x * 64;
  const int rbase = row0 + wr * 32;

  f32x4 acc[2][6];
#pragma unroll
  for (int mi = 0; mi < 2; ++mi)
#pragma unroll
    for (int ni = 0; ni < 6; ++ni)
#pragma unroll
      for (int r = 0; r < 4; ++r) acc[mi][ni][r] = 0.f;

#pragma unroll 2
  for (int kt = 0; kt < 12; ++kt) {
    // A fragments: 8 consecutive fp32 of x -> bf16x8 (HW pk-cvt).
    bf16x8 a[2];
#pragma unroll
    for (int mi = 0; mi < 2; ++mi) {
      const float* xp =
          x + (size_t)(rbase + mi * 16 + l15) * NC + kt * 32 + lg * 8;
      const float4 x0 = *reinterpret_cast<const float4*>(xp);
      const float4 x1 = *reinterpret_cast<const float4*>(xp + 4);
      union { bf16x8 v; unsigned short u[8]; } au;
      au.u[0] = f2bf_hw(x0.x);
      au.u[1] = f2bf_hw(x0.y);
      au.u[2] = f2bf_hw(x0.z);
      au.u[3] = f2bf_hw(x0.w);
      au.u[4] = f2bf_hw(x1.x);
      au.u[5] = f2bf_hw(x1.y);
      au.u[6] = f2bf_hw(x1.z);
      au.u[7] = f2bf_hw(x1.w);
      a[mi] = au.v;
    }
    // B fragments from Wt (row n, contiguous k) + MFMA.
#pragma unroll
    for (int ni = 0; ni < 6; ++ni) {
      const bf16x8 bfrag = *reinterpret_cast<const bf16x8*>(
          Wt + (size_t)(wc * 96 + ni * 16 + l15) * NC + kt * 32 + lg * 8);
      acc[0][ni] = __builtin_amdgcn_mfma_f32_16x16x32_bf16(
          a[0], bfrag, acc[0][ni], 0, 0, 0);
      acc[1][ni] = __builtin_amdgcn_mfma_f32_16x16x32_bf16(
          a[1], bfrag, acc[1][ni], 0, 0, 0);
    }
  }

  // Epilogue 1: D-layout fragments -> padded LDS tile.
#pragma unroll
  for (int mi = 0; mi < 2; ++mi)
#pragma unroll
    for (int ni = 0; ni < 6; ++ni) {
      const int col = wc * 96 + ni * 16 + l15;
#pragma unroll
      for (int r = 0; r < 4; ++r) {
        const int lrow = wr * 32 + mi * 16 + lg * 4 + r;
        Sls[lrow * SROW + col] = f2bf_hw(acc[mi][ni][r]);
      }
    }
  __syncthreads();

  // Epilogue 2: coalesced 16B stores. 1536 chunks of 8 shorts; 6/thread.
#pragma unroll
  for (int i = 0; i < 6; ++i) {
    const int c = i * 256 + tid;
    const int lrow = c / 24;        // 24 chunks per 192-col row
    const int nc = c - lrow * 24;
    const int n0 = nc * 8;
    const uint4 v = *reinterpret_cast<const uint4*>(&Sls[lrow * SROW + n0]);
    *reinterpret_cast<uint4*>(
        qkv + (size_t)(n0 >> 6) * NQ + (size_t)(row0 + lrow) * NH + (n0 & 63)) = v;
  }
}

// ---------------------------------------------------------------------------
// Kernel 2: MFMA causal flash attention (unchanged; ~4 us).
// ---------------------------------------------------------------------------
__global__ __launch_bounds__(512) void attn_mfma_kernel(
    const unsigned short* __restrict__ qkv,
    float* __restrict__ out) {
  __shared__ unsigned short Kls[NT * NH];
  __shared__ unsigned short Vtls[NH * NT];
  __shared__ unsigned short Pls[8][32 * 40];

  const int b = blockIdx.x;
  const int tid = threadIdx.x;
  const int w = tid >> 6;
  const int lane = tid & 63;
  const int l15 = lane & 15;
  const int lg = lane >> 4;

  const unsigned short* Qg = qkv + (size_t)b * NT * NH;
  const unsigned short* Kg = Qg + NQ;
  const unsigned short* Vg = Qg + 2 * NQ;

#pragma unroll
  for (int it = 0; it < 4; ++it) {
    const int idx = it * 512 + tid;
    const int row = idx >> 3, ch = idx & 7;
    *reinterpret_cast<uint4*>(&Kls[row * 64 + ((ch * 8) ^ ((row & 7) << 3))]) =
        *reinterpret_cast<const uint4*>(Kg + row * 64 + ch * 8);
  }
  {
    const int s = tid & 255, hq = tid >> 8;
#pragma unroll
    for (int c = 0; c < 4; ++c) {
      unsigned short va[8];
      *reinterpret_cast<uint4*>(va) =
          *reinterpret_cast<const uint4*>(Vg + s * 64 + hq * 32 + c * 8);
#pragma unroll
      for (int i = 0; i < 8; ++i) {
        const int h = hq * 32 + c * 8 + i;
        Vtls[h * 256 + (s ^ ((h & 7) << 3))] = va[i];
      }
    }
  }
  __syncthreads();

  const int qt = (w < 4) ? w : 11 - w;
  const int q0 = qt * 32;

  bf16x8 a_q[2][2];
#pragma unroll
  for (int mi = 0; mi < 2; ++mi)
#pragma unroll
    for (int ks = 0; ks < 2; ++ks)
      a_q[mi][ks] = *reinterpret_cast<const bf16x8*>(
          Qg + (q0 + mi * 16 + l15) * 64 + ks * 32 + lg * 8);

  f32x4 o[2][4];
  float mrun[2][4], lrun[2][4];
#pragma unroll
  for (int mi = 0; mi < 2; ++mi)
#pragma unroll
    for (int r = 0; r < 4; ++r) {
      mrun[mi][r] = -3.0e38f;
      lrun[mi][r] = 0.f;
#pragma unroll
      for (int hi = 0; hi < 4; ++hi) o[mi][hi][r] = 0.f;
    }

  for (int j = 0; j <= qt; ++j) {
    f32x4 s_acc[2][2];
#pragma unroll
    for (int mi = 0; mi < 2; ++mi)
#pragma unroll
      for (int si = 0; si < 2; ++si)
#pragma unroll
        for (int r = 0; r < 4; ++r) s_acc[mi][si][r] = 0.f;

#pragma unroll
    for (int ks = 0; ks < 2; ++ks) {
      bf16x8 bk[2];
#pragma unroll
      for (int si = 0; si < 2; ++si) {
        const int srow = j * 32 + si * 16 + l15;
        const int kel = ks * 32 + lg * 8;
        bk[si] = *reinterpret_cast<const bf16x8*>(
            &Kls[srow * 64 + (kel ^ ((srow & 7) << 3))]);
      }
#pragma unroll
      for (int mi = 0; mi < 2; ++mi)
#pragma unroll
        for (int si = 0; si < 2; ++si)
          s_acc[mi][si] = __builtin_amdgcn_mfma_f32_16x16x32_bf16(
              a_q[mi][ks], bk[si], s_acc[mi][si], 0, 0, 0);
    }

    const bool diag = (j == qt);
#pragma unroll
    for (int mi = 0; mi < 2; ++mi) {
#pragma unroll
      for (int r = 0; r < 4; ++r) {
        const int mloc = mi * 16 + lg * 4 + r;
        float v0 = s_acc[mi][0][r] * 0.125f;
        float v1 = s_acc[mi][1][r] * 0.125f;
        if (diag) {
          if (l15 > mloc) v0 = -3.0e38f;
          if (16 + l15 > mloc) v1 = -3.0e38f;
        }
        float pm = fmaxf(v0, v1);
        pm = fmaxf(pm, __shfl_xor(pm, 1, 16));
        pm = fmaxf(pm, __shfl_xor(pm, 2, 16));
        pm = fmaxf(pm, __shfl_xor(pm, 4, 16));
        pm = fmaxf(pm, __shfl_xor(pm, 8, 16));
        const float mnew = fmaxf(mrun[mi][r], pm);
        const float alpha = __expf(mrun[mi][r] - mnew);
        mrun[mi][r] = mnew;
        const float p0 = __expf(v0 - mnew);
        const float p1 = __expf(v1 - mnew);
        float ps = p0 + p1;
        ps += __shfl_xor(ps, 1, 16);
        ps += __shfl_xor(ps, 2, 16);
        ps += __shfl_xor(ps, 4, 16);
        ps += __shfl_xor(ps, 8, 16);
        lrun[mi][r] = lrun[mi][r] * alpha + ps;
#pragma unroll
        for (int hi = 0; hi < 4; ++hi) o[mi][hi][r] *= alpha;
        Pls[w][mloc * 40 + l15] = f2bf(p0);
        Pls[w][mloc * 40 + 16 + l15] = f2bf(p1);
      }
    }

    bf16x8 pa[2];
#pragma unroll
    for (int mt = 0; mt < 2; ++mt)
      pa[mt] = *reinterpret_cast<const bf16x8*>(
          &Pls[w][(mt * 16 + l15) * 40 + lg * 8]);
#pragma unroll
    for (int hi = 0; hi < 4; ++hi) {
      const int h = hi * 16 + l15;
      const int sel = j * 32 + lg * 8;
      const bf16x8 bv = *reinterpret_cast<const bf16x8*>(
          &Vtls[h * 256 + (sel ^ ((h & 7) << 3))]);
#pragma unroll
      for (int mt = 0; mt < 2; ++mt)
        o[mt][hi] = __builtin_amdgcn_mfma_f32_16x16x32_bf16(
            pa[mt], bv, o[mt][hi], 0, 0, 0);
    }
  }

  float* og = out + ((size_t)b * NT + q0) * NH;
#pragma unroll
  for (int mi = 0; mi < 2; ++mi)
#pragma unroll
    for (int r = 0; r < 4; ++r) {
      const float inv = 1.f / lrun[mi][r];
      const int m = mi * 16 + lg * 4 + r;
#pragma unroll
      for (int hi = 0; hi < 4; ++hi)
        og[m * 64 + hi * 16 + l15] = o[mi][hi][r] * inv;
    }
}

// ---------------------------------------------------------------------------
extern "C" void kernel_launch(void* const* d_in, const int* in_sizes, int n_in,
                              void* d_out, int out_size, void* d_ws,
                              size_t ws_size, hipStream_t stream) {
  const float* x  = (const float*)d_in[0];
  const float* Wq = (const float*)d_in[1];
  const float* Wk = (const float*)d_in[2];
  const float* Wv = (const float*)d_in[3];
  unsigned short* Wt  = (unsigned short*)d_ws;            // 147 KB
  unsigned short* qkv = (unsigned short*)d_ws + WT_ELEMS; // 25.2 MB
  float* out = (float*)d_out;

  w_transpose_kernel<<<dim3((WT_ELEMS + 255) / 256), dim3(256), 0, stream>>>(
      Wq, Wk, Wv, Wt);
  qkv_proj_mfma<<<dim3(1024), dim3(256), 0, stream>>>(x, Wt, qkv);
  attn_mfma_kernel<<<dim3(NB), dim3(512), 0, stream>>>(qkv, out);
}

// Round 5
// 72.578 us; speedup vs baseline: 1.1778x; 1.1778x over previous
//
#include <hip/hip_runtime.h>
#include <hip/hip_bf16.h>

// Problem constants (B, T, C, HS) from the reference.
#define NB 256
#define NT 256
#define NC 384
#define NH 64
#define NQ (NB * NT * NH)   // elements per q/k/v tensor = 4194304
#define NW 192              // 3 * NH concatenated output cols
#define WT_ELEMS (NW * NC)  // Wt bf16 elements = 73728

typedef short bf16x8 __attribute__((ext_vector_type(8)));
typedef float f32x4 __attribute__((ext_vector_type(4)));

__device__ __forceinline__ float bf2f(unsigned short u) {
  union { unsigned int i; float f; } c;
  c.i = ((unsigned int)u) << 16;
  return c.f;
}

__device__ __forceinline__ unsigned short f2bf(float f) {
  union { float f; unsigned int i; } c;
  c.f = f;
  const unsigned int r = c.i + 0x7fffu + ((c.i >> 16) & 1u);
  return (unsigned short)(r >> 16);
}

__device__ __forceinline__ unsigned short f2bf_hw(float f) {
  __hip_bfloat16 b = __float2bfloat16(f);
  return *reinterpret_cast<unsigned short*>(&b);
}

// ---------------------------------------------------------------------------
// Kernel 0: transpose + convert weights. Wt[n][k] bf16 [192][384].
// ---------------------------------------------------------------------------
__global__ __launch_bounds__(256) void w_transpose_kernel(
    const float* __restrict__ Wq,
    const float* __restrict__ Wk,
    const float* __restrict__ Wv,
    unsigned short* __restrict__ Wt) {
  const int idx = blockIdx.x * 256 + threadIdx.x;
  if (idx >= WT_ELEMS) return;
  const int n = idx / NC, k = idx - n * NC;
  const float* W = (n < 64) ? Wq : (n < 128) ? Wk : Wv;
  Wt[idx] = f2bf(W[k * NH + (n & 63)]);
}

// ---------------------------------------------------------------------------
// Kernel 1: fused QKV projection, m97-structure (round 5).
//   [65536 x 384] (x fp32, staged via global_load_lds) @ Wt[384x192] -> qkv.
// Block = 512 thr = 8 waves (wr=w>>1 row quarter, wc=w&1 col half).
// Tile 128 rows x 192 cols, BK=64 (6 k-steps), x double-buffered in LDS
// (2 x 32 KB fp32). Source-pre-swizzled staging (slot ^= row&7 within each
// 8-slot half of the 256B row) makes A ds_read_b128 conflict-free
// (8 words/bank uniform). Wt B-frags load direct from L2 (147 KB resident).
// acc[2][6] = 48 VGPR; ks-split inner loop keeps live regs ~110 under the
// __launch_bounds__(512,4) cap -> 2 blocks/CU, 16 waves/CU.
// Epilogue: LDS bounce (reuse staging buffer) -> coalesced uint4 stores.
// ---------------------------------------------------------------------------
#define SROW 208  // bounce row stride in shorts
__global__ __launch_bounds__(512, 4) void qkv_proj_mfma(
    const float* __restrict__ x,
    const unsigned short* __restrict__ Wt,
    unsigned short* __restrict__ qkv) {
  __shared__ float Xls[2][128 * 64];  // 64 KB total

  const int tid = threadIdx.x;
  const int w = tid >> 6;
  const int lane = tid & 63;
  const int l15 = lane & 15;
  const int lg = lane >> 4;
  const int wr = w >> 1;   // row quarter 0..3
  const int wc = w & 1;    // col half 0..1
  const int row0 = blockIdx.x * 128;

  f32x4 acc[2][6];
#pragma unroll
  for (int mi = 0; mi < 2; ++mi)
#pragma unroll
    for (int ni = 0; ni < 6; ++ni)
#pragma unroll
      for (int r = 0; r < 4; ++r) acc[mi][ni][r] = 0.f;

  // Stage one 128x64 fp32 k-slice of x into Xls[buf], source-pre-swizzled.
  // Chunk idx in [0,2048): row = idx>>4, physical 16B slot c = idx&15.
  // Physical slot c holds logical slot (c&8) | ((c&7) ^ (row&7)).
#define STAGE(buf, kt)                                                        \
  {                                                                           \
    _Pragma("unroll")                                                         \
    for (int j = 0; j < 4; ++j) {                                             \
      const int idx = j * 512 + tid;                                          \
      const int srow = idx >> 4, c = idx & 15;                                \
      const int q = c >> 3, cw = c & 7;                                       \
      const float* src = x + (size_t)(row0 + srow) * NC + (kt)*64 + q * 32 +  \
                         ((cw ^ (srow & 7)) << 2);                            \
      __builtin_amdgcn_global_load_lds(                                       \
          (const __attribute__((address_space(1))) void*)src,                 \
          (__attribute__((address_space(3))) void*)&Xls[buf][idx * 4], 16, 0, \
          0);                                                                 \
    }                                                                         \
  }

  STAGE(0, 0);
  __syncthreads();

  for (int kt = 0; kt < 6; ++kt) {
    const int cur = kt & 1;
    if (kt < 5) STAGE(cur ^ 1, kt + 1);

#pragma unroll
    for (int ks = 0; ks < 2; ++ks) {
      // B fragments from Wt (row n, contiguous k), L2-warm.
      bf16x8 bfr[6];
#pragma unroll
      for (int ni = 0; ni < 6; ++ni)
        bfr[ni] = *reinterpret_cast<const bf16x8*>(
            Wt + (size_t)(wc * 96 + ni * 16 + l15) * NC + kt * 64 + ks * 32 +
            lg * 8);
      // A fragments from LDS (swizzled), cvt fp32->bf16.
      bf16x8 afr[2];
#pragma unroll
      for (int mi = 0; mi < 2; ++mi) {
        const int rl = wr * 32 + mi * 16 + l15;
        const int s0 = ks * 8 + ((lg * 2) ^ (rl & 7));
        const int s1 = ks * 8 + ((lg * 2 + 1) ^ (rl & 7));
        const float4 lo =
            *reinterpret_cast<const float4*>(&Xls[cur][rl * 64 + s0 * 4]);
        const float4 hi =
            *reinterpret_cast<const float4*>(&Xls[cur][rl * 64 + s1 * 4]);
        union { bf16x8 v; unsigned short u[8]; } au;
        au.u[0] = f2bf_hw(lo.x);
        au.u[1] = f2bf_hw(lo.y);
        au.u[2] = f2bf_hw(lo.z);
        au.u[3] = f2bf_hw(lo.w);
        au.u[4] = f2bf_hw(hi.x);
        au.u[5] = f2bf_hw(hi.y);
        au.u[6] = f2bf_hw(hi.z);
        au.u[7] = f2bf_hw(hi.w);
        afr[mi] = au.v;
      }
#pragma unroll
      for (int ni = 0; ni < 6; ++ni) {
        acc[0][ni] = __builtin_amdgcn_mfma_f32_16x16x32_bf16(
            afr[0], bfr[ni], acc[0][ni], 0, 0, 0);
        acc[1][ni] = __builtin_amdgcn_mfma_f32_16x16x32_bf16(
            afr[1], bfr[ni], acc[1][ni], 0, 0, 0);
      }
    }
    __syncthreads();
  }

  // Epilogue: bounce through LDS (reuse staging memory), coalesced stores.
  unsigned short* Sls = reinterpret_cast<unsigned short*>(&Xls[0][0]);
#pragma unroll
  for (int mi = 0; mi < 2; ++mi)
#pragma unroll
    for (int ni = 0; ni < 6; ++ni) {
      const int col = wc * 96 + ni * 16 + l15;
#pragma unroll
      for (int r = 0; r < 4; ++r) {
        const int lrow = wr * 32 + mi * 16 + lg * 4 + r;
        Sls[lrow * SROW + col] = f2bf_hw(acc[mi][ni][r]);
      }
    }
  __syncthreads();

  // 128 rows x 192 cols = 3072 uint4 chunks; 6 per thread.
#pragma unroll
  for (int i = 0; i < 6; ++i) {
    const int c = i * 512 + tid;
    const int lrow = c / 24;
    const int nc = c - lrow * 24;
    const int n0 = nc * 8;
    const uint4 v = *reinterpret_cast<const uint4*>(&Sls[lrow * SROW + n0]);
    *reinterpret_cast<uint4*>(qkv + (size_t)(n0 >> 6) * NQ +
                              (size_t)(row0 + lrow) * NH + (n0 & 63)) = v;
  }
}

// ---------------------------------------------------------------------------
// Kernel 2: MFMA causal flash attention (unchanged).
// ---------------------------------------------------------------------------
__global__ __launch_bounds__(512) void attn_mfma_kernel(
    const unsigned short* __restrict__ qkv,
    float* __restrict__ out) {
  __shared__ unsigned short Kls[NT * NH];
  __shared__ unsigned short Vtls[NH * NT];
  __shared__ unsigned short Pls[8][32 * 40];

  const int b = blockIdx.x;
  const int tid = threadIdx.x;
  const int w = tid >> 6;
  const int lane = tid & 63;
  const int l15 = lane & 15;
  const int lg = lane >> 4;

  const unsigned short* Qg = qkv + (size_t)b * NT * NH;
  const unsigned short* Kg = Qg + NQ;
  const unsigned short* Vg = Qg + 2 * NQ;

#pragma unroll
  for (int it = 0; it < 4; ++it) {
    const int idx = it * 512 + tid;
    const int row = idx >> 3, ch = idx & 7;
    *reinterpret_cast<uint4*>(&Kls[row * 64 + ((ch * 8) ^ ((row & 7) << 3))]) =
        *reinterpret_cast<const uint4*>(Kg + row * 64 + ch * 8);
  }
  {
    const int s = tid & 255, hq = tid >> 8;
#pragma unroll
    for (int c = 0; c < 4; ++c) {
      unsigned short va[8];
      *reinterpret_cast<uint4*>(va) =
          *reinterpret_cast<const uint4*>(Vg + s * 64 + hq * 32 + c * 8);
#pragma unroll
      for (int i = 0; i < 8; ++i) {
        const int h = hq * 32 + c * 8 + i;
        Vtls[h * 256 + (s ^ ((h & 7) << 3))] = va[i];
      }
    }
  }
  __syncthreads();

  const int qt = (w < 4) ? w : 11 - w;
  const int q0 = qt * 32;

  bf16x8 a_q[2][2];
#pragma unroll
  for (int mi = 0; mi < 2; ++mi)
#pragma unroll
    for (int ks = 0; ks < 2; ++ks)
      a_q[mi][ks] = *reinterpret_cast<const bf16x8*>(
          Qg + (q0 + mi * 16 + l15) * 64 + ks * 32 + lg * 8);

  f32x4 o[2][4];
  float mrun[2][4], lrun[2][4];
#pragma unroll
  for (int mi = 0; mi < 2; ++mi)
#pragma unroll
    for (int r = 0; r < 4; ++r) {
      mrun[mi][r] = -3.0e38f;
      lrun[mi][r] = 0.f;
#pragma unroll
      for (int hi = 0; hi < 4; ++hi) o[mi][hi][r] = 0.f;
    }

  for (int j = 0; j <= qt; ++j) {
    f32x4 s_acc[2][2];
#pragma unroll
    for (int mi = 0; mi < 2; ++mi)
#pragma unroll
      for (int si = 0; si < 2; ++si)
#pragma unroll
        for (int r = 0; r < 4; ++r) s_acc[mi][si][r] = 0.f;

#pragma unroll
    for (int ks = 0; ks < 2; ++ks) {
      bf16x8 bk[2];
#pragma unroll
      for (int si = 0; si < 2; ++si) {
        const int srow = j * 32 + si * 16 + l15;
        const int kel = ks * 32 + lg * 8;
        bk[si] = *reinterpret_cast<const bf16x8*>(
            &Kls[srow * 64 + (kel ^ ((srow & 7) << 3))]);
      }
#pragma unroll
      for (int mi = 0; mi < 2; ++mi)
#pragma unroll
        for (int si = 0; si < 2; ++si)
          s_acc[mi][si] = __builtin_amdgcn_mfma_f32_16x16x32_bf16(
              a_q[mi][ks], bk[si], s_acc[mi][si], 0, 0, 0);
    }

    const bool diag = (j == qt);
#pragma unroll
    for (int mi = 0; mi < 2; ++mi) {
#pragma unroll
      for (int r = 0; r < 4; ++r) {
        const int mloc = mi * 16 + lg * 4 + r;
        float v0 = s_acc[mi][0][r] * 0.125f;
        float v1 = s_acc[mi][1][r] * 0.125f;
        if (diag) {
          if (l15 > mloc) v0 = -3.0e38f;
          if (16 + l15 > mloc) v1 = -3.0e38f;
        }
        float pm = fmaxf(v0, v1);
        pm = fmaxf(pm, __shfl_xor(pm, 1, 16));
        pm = fmaxf(pm, __shfl_xor(pm, 2, 16));
        pm = fmaxf(pm, __shfl_xor(pm, 4, 16));
        pm = fmaxf(pm, __shfl_xor(pm, 8, 16));
        const float mnew = fmaxf(mrun[mi][r], pm);
        const float alpha = __expf(mrun[mi][r] - mnew);
        mrun[mi][r] = mnew;
        const float p0 = __expf(v0 - mnew);
        const float p1 = __expf(v1 - mnew);
        float ps = p0 + p1;
        ps += __shfl_xor(ps, 1, 16);
        ps += __shfl_xor(ps, 2, 16);
        ps += __shfl_xor(ps, 4, 16);
        ps += __shfl_xor(ps, 8, 16);
        lrun[mi][r] = lrun[mi][r] * alpha + ps;
#pragma unroll
        for (int hi = 0; hi < 4; ++hi) o[mi][hi][r] *= alpha;
        Pls[w][mloc * 40 + l15] = f2bf(p0);
        Pls[w][mloc * 40 + 16 + l15] = f2bf(p1);
      }
    }

    bf16x8 pa[2];
#pragma unroll
    for (int mt = 0; mt < 2; ++mt)
      pa[mt] = *reinterpret_cast<const bf16x8*>(
          &Pls[w][(mt * 16 + l15) * 40 + lg * 8]);
#pragma unroll
    for (int hi = 0; hi < 4; ++hi) {
      const int h = hi * 16 + l15;
      const int sel = j * 32 + lg * 8;
      const bf16x8 bv = *reinterpret_cast<const bf16x8*>(
          &Vtls[h * 256 + (sel ^ ((h & 7) << 3))]);
#pragma unroll
      for (int mt = 0; mt < 2; ++mt)
        o[mt][hi] = __builtin_amdgcn_mfma_f32_16x16x32_bf16(
            pa[mt], bv, o[mt][hi], 0, 0, 0);
    }
  }

  float* og = out + ((size_t)b * NT + q0) * NH;
#pragma unroll
  for (int mi = 0; mi < 2; ++mi)
#pragma unroll
    for (int r = 0; r < 4; ++r) {
      const float inv = 1.f / lrun[mi][r];
      const int m = mi * 16 + lg * 4 + r;
#pragma unroll
      for (int hi = 0; hi < 4; ++hi)
        og[m * 64 + hi * 16 + l15] = o[mi][hi][r] * inv;
    }
}

// ---------------------------------------------------------------------------
extern "C" void kernel_launch(void* const* d_in, const int* in_sizes, int n_in,
                              void* d_out, int out_size, void* d_ws,
                              size_t ws_size, hipStream_t stream) {
  const float* x  = (const float*)d_in[0];
  const float* Wq = (const float*)d_in[1];
  const float* Wk = (const float*)d_in[2];
  const float* Wv = (const float*)d_in[3];
  unsigned short* Wt  = (unsigned short*)d_ws;            // 147 KB
  unsigned short* qkv = (unsigned short*)d_ws + WT_ELEMS; // 25.2 MB
  float* out = (float*)d_out;

  w_transpose_kernel<<<dim3((WT_ELEMS + 255) / 256), dim3(256), 0, stream>>>(
      Wq, Wk, Wv, Wt);
  qkv_proj_mfma<<<dim3(512), dim3(512), 0, stream>>>(x, Wt, qkv);
  attn_mfma_kernel<<<dim3(NB), dim3(512), 0, stream>>>(qkv, out);
}

// Round 6
// 57.320 us; speedup vs baseline: 1.4913x; 1.2662x over previous
//
#include <hip/hip_runtime.h>
#include <hip/hip_bf16.h>

// Problem constants (B, T, C, HS) from the reference.
#define NB 256
#define NT 256
#define NC 384
#define NH 64
#define NQ (NB * NT * NH)   // elements per q/k/v tensor = 4194304
#define NW 192              // 3 * NH concatenated output cols
#define WT_ELEMS (NW * NC)  // Wt bf16 elements = 73728

typedef short bf16x8 __attribute__((ext_vector_type(8)));
typedef float f32x4 __attribute__((ext_vector_type(4)));

__device__ __forceinline__ float bf2f(unsigned short u) {
  union { unsigned int i; float f; } c;
  c.i = ((unsigned int)u) << 16;
  return c.f;
}

__device__ __forceinline__ unsigned short f2bf(float f) {
  union { float f; unsigned int i; } c;
  c.f = f;
  const unsigned int r = c.i + 0x7fffu + ((c.i >> 16) & 1u);
  return (unsigned short)(r >> 16);
}

__device__ __forceinline__ unsigned short f2bf_hw(float f) {
  __hip_bfloat16 b = __float2bfloat16(f);
  return *reinterpret_cast<unsigned short*>(&b);
}

// ---------------------------------------------------------------------------
// Kernel 0: transpose + convert weights. Wt[n][k] bf16 [192][384].
// ---------------------------------------------------------------------------
__global__ __launch_bounds__(256) void w_transpose_kernel(
    const float* __restrict__ Wq,
    const float* __restrict__ Wk,
    const float* __restrict__ Wv,
    unsigned short* __restrict__ Wt) {
  const int idx = blockIdx.x * 256 + threadIdx.x;
  if (idx >= WT_ELEMS) return;
  const int n = idx / NC, k = idx - n * NC;
  const float* W = (n < 64) ? Wq : (n < 128) ? Wk : Wv;
  Wt[idx] = f2bf(W[k * NH + (n & 63)]);
}

// ---------------------------------------------------------------------------
// Kernel 1: fused QKV projection (round 6): ALL global reads are contiguous
// global_load_lds; all fragment reads come from LDS.
//   Rounds 3-5 post-mortem: divergent global register loads (16 rows/wave,
//   stride 768B) made the kernel TA/L1-transaction-bound (~43K line reqs/CU
//   ~= 72 us) — invisible in VALUBusy/MfmaUtil. Fix: W k-slice staged to LDS
//   per k-step (contiguous, double-buffered) like x.
// Block = 512 thr = 8 waves (wr=w>>1 row quarter, wc=w&1 col half).
// Tile 128 rows x 192 cols, BK=64 (6 k-steps).
// LDS: Xls 2x32KB (fp32 x-slice) + Wls 2x24KB (bf16 W-slice) = 112 KB
//   -> 1 block/CU, 8 waves (2/SIMD), __launch_bounds__(512,2).
// Both stagings source-pre-swizzled (16B chunk c holds logical c^(row&7))
// so ds_read_b128 fragment reads are 2-way (free) bank-spread.
// Epilogue: bounce through Xls (53 KB) -> coalesced uint4 stores.
// ---------------------------------------------------------------------------
#define SROW 208  // bounce row stride in shorts
__global__ __launch_bounds__(512, 2) void qkv_proj_mfma(
    const float* __restrict__ x,
    const unsigned short* __restrict__ Wt,
    unsigned short* __restrict__ qkv) {
  __shared__ float Xls[2][128 * 64];           // 64 KB
  __shared__ unsigned short Wls[2][192 * 64];  // 48 KB

  const int tid = threadIdx.x;
  const int w = tid >> 6;
  const int lane = tid & 63;
  const int l15 = lane & 15;
  const int lg = lane >> 4;
  const int wr = w >> 1;   // row quarter 0..3
  const int wc = w & 1;    // col half 0..1
  const int row0 = blockIdx.x * 128;

  f32x4 acc[2][6];
#pragma unroll
  for (int mi = 0; mi < 2; ++mi)
#pragma unroll
    for (int ni = 0; ni < 6; ++ni)
#pragma unroll
      for (int r = 0; r < 4; ++r) acc[mi][ni][r] = 0.f;

  // Stage a 128x64 fp32 x-slice. Chunk idx: row=idx>>4, phys 16B slot
  // c=idx&15 holds logical slot (c&8)|((c&7)^(row&7)). Contiguous 256B/row.
#define STAGE_X(buf, kt)                                                      \
  {                                                                           \
    _Pragma("unroll")                                                         \
    for (int j = 0; j < 4; ++j) {                                             \
      const int idx = j * 512 + tid;                                          \
      const int srow = idx >> 4, c = idx & 15;                                \
      const int q = c >> 3, cw = c & 7;                                       \
      const float* src = x + (size_t)(row0 + srow) * NC + (kt)*64 + q * 32 +  \
                         ((cw ^ (srow & 7)) << 2);                            \
      __builtin_amdgcn_global_load_lds(                                       \
          (const __attribute__((address_space(1))) void*)src,                 \
          (__attribute__((address_space(3))) void*)&Xls[buf][idx * 4], 16, 0, \
          0);                                                                 \
    }                                                                         \
  }

  // Stage a 192x64 bf16 W-slice (cols kt*64..+64 of Wt). 1536 chunks of
  // 16B = 3/thread; row=idx>>3, phys chunk c=idx&7 holds logical c^(row&7).
  // Contiguous 128B per row.
#define STAGE_W(buf, kt)                                                     \
  {                                                                          \
    _Pragma("unroll")                                                        \
    for (int j = 0; j < 3; ++j) {                                            \
      const int idx = j * 512 + tid;                                         \
      const int nrow = idx >> 3, c = idx & 7;                                \
      const unsigned short* src = Wt + (size_t)nrow * NC + (kt)*64 +         \
                                  ((c ^ (nrow & 7)) << 3);                   \
      __builtin_amdgcn_global_load_lds(                                      \
          (const __attribute__((address_space(1))) void*)src,                \
          (__attribute__((address_space(3))) void*)&Wls[buf][idx * 8], 16,   \
          0, 0);                                                             \
    }                                                                        \
  }

  STAGE_X(0, 0);
  STAGE_W(0, 0);
  __syncthreads();

  for (int kt = 0; kt < 6; ++kt) {
    const int cur = kt & 1;
    if (kt < 5) {
      STAGE_X(cur ^ 1, kt + 1);
      STAGE_W(cur ^ 1, kt + 1);
    }

#pragma unroll
    for (int ks = 0; ks < 2; ++ks) {
      // B fragments from Wls (swizzled): n-row per l15, 16B chunk per lg.
      bf16x8 bfr[6];
#pragma unroll
      for (int ni = 0; ni < 6; ++ni) {
        const int n = wc * 96 + ni * 16 + l15;
        const int kel = (ks * 32 + lg * 8) ^ ((n & 7) << 3);
        bfr[ni] = *reinterpret_cast<const bf16x8*>(&Wls[cur][n * 64 + kel]);
      }
      // A fragments from Xls (swizzled), cvt fp32->bf16.
      bf16x8 afr[2];
#pragma unroll
      for (int mi = 0; mi < 2; ++mi) {
        const int rl = wr * 32 + mi * 16 + l15;
        const int s0 = ks * 8 + ((lg * 2) ^ (rl & 7));
        const int s1 = ks * 8 + ((lg * 2 + 1) ^ (rl & 7));
        const float4 lo =
            *reinterpret_cast<const float4*>(&Xls[cur][rl * 64 + s0 * 4]);
        const float4 hi =
            *reinterpret_cast<const float4*>(&Xls[cur][rl * 64 + s1 * 4]);
        union { bf16x8 v; unsigned short u[8]; } au;
        au.u[0] = f2bf_hw(lo.x);
        au.u[1] = f2bf_hw(lo.y);
        au.u[2] = f2bf_hw(lo.z);
        au.u[3] = f2bf_hw(lo.w);
        au.u[4] = f2bf_hw(hi.x);
        au.u[5] = f2bf_hw(hi.y);
        au.u[6] = f2bf_hw(hi.z);
        au.u[7] = f2bf_hw(hi.w);
        afr[mi] = au.v;
      }
#pragma unroll
      for (int ni = 0; ni < 6; ++ni) {
        acc[0][ni] = __builtin_amdgcn_mfma_f32_16x16x32_bf16(
            afr[0], bfr[ni], acc[0][ni], 0, 0, 0);
        acc[1][ni] = __builtin_amdgcn_mfma_f32_16x16x32_bf16(
            afr[1], bfr[ni], acc[1][ni], 0, 0, 0);
      }
    }
    __syncthreads();
  }

  // Epilogue: bounce through LDS (reuse Xls), coalesced stores.
  unsigned short* Sls = reinterpret_cast<unsigned short*>(&Xls[0][0]);
#pragma unroll
  for (int mi = 0; mi < 2; ++mi)
#pragma unroll
    for (int ni = 0; ni < 6; ++ni) {
      const int col = wc * 96 + ni * 16 + l15;
#pragma unroll
      for (int r = 0; r < 4; ++r) {
        const int lrow = wr * 32 + mi * 16 + lg * 4 + r;
        Sls[lrow * SROW + col] = f2bf_hw(acc[mi][ni][r]);
      }
    }
  __syncthreads();

  // 128 rows x 192 cols = 3072 uint4 chunks; 6 per thread.
#pragma unroll
  for (int i = 0; i < 6; ++i) {
    const int c = i * 512 + tid;
    const int lrow = c / 24;
    const int nc = c - lrow * 24;
    const int n0 = nc * 8;
    const uint4 v = *reinterpret_cast<const uint4*>(&Sls[lrow * SROW + n0]);
    *reinterpret_cast<uint4*>(qkv + (size_t)(n0 >> 6) * NQ +
                              (size_t)(row0 + lrow) * NH + (n0 & 63)) = v;
  }
}

// ---------------------------------------------------------------------------
// Kernel 2: MFMA causal flash attention (unchanged).
// ---------------------------------------------------------------------------
__global__ __launch_bounds__(512) void attn_mfma_kernel(
    const unsigned short* __restrict__ qkv,
    float* __restrict__ out) {
  __shared__ unsigned short Kls[NT * NH];
  __shared__ unsigned short Vtls[NH * NT];
  __shared__ unsigned short Pls[8][32 * 40];

  const int b = blockIdx.x;
  const int tid = threadIdx.x;
  const int w = tid >> 6;
  const int lane = tid & 63;
  const int l15 = lane & 15;
  const int lg = lane >> 4;

  const unsigned short* Qg = qkv + (size_t)b * NT * NH;
  const unsigned short* Kg = Qg + NQ;
  const unsigned short* Vg = Qg + 2 * NQ;

#pragma unroll
  for (int it = 0; it < 4; ++it) {
    const int idx = it * 512 + tid;
    const int row = idx >> 3, ch = idx & 7;
    *reinterpret_cast<uint4*>(&Kls[row * 64 + ((ch * 8) ^ ((row & 7) << 3))]) =
        *reinterpret_cast<const uint4*>(Kg + row * 64 + ch * 8);
  }
  {
    const int s = tid & 255, hq = tid >> 8;
#pragma unroll
    for (int c = 0; c < 4; ++c) {
      unsigned short va[8];
      *reinterpret_cast<uint4*>(va) =
          *reinterpret_cast<const uint4*>(Vg + s * 64 + hq * 32 + c * 8);
#pragma unroll
      for (int i = 0; i < 8; ++i) {
        const int h = hq * 32 + c * 8 + i;
        Vtls[h * 256 + (s ^ ((h & 7) << 3))] = va[i];
      }
    }
  }
  __syncthreads();

  const int qt = (w < 4) ? w : 11 - w;
  const int q0 = qt * 32;

  bf16x8 a_q[2][2];
#pragma unroll
  for (int mi = 0; mi < 2; ++mi)
#pragma unroll
    for (int ks = 0; ks < 2; ++ks)
      a_q[mi][ks] = *reinterpret_cast<const bf16x8*>(
          Qg + (q0 + mi * 16 + l15) * 64 + ks * 32 + lg * 8);

  f32x4 o[2][4];
  float mrun[2][4], lrun[2][4];
#pragma unroll
  for (int mi = 0; mi < 2; ++mi)
#pragma unroll
    for (int r = 0; r < 4; ++r) {
      mrun[mi][r] = -3.0e38f;
      lrun[mi][r] = 0.f;
#pragma unroll
      for (int hi = 0; hi < 4; ++hi) o[mi][hi][r] = 0.f;
    }

  for (int j = 0; j <= qt; ++j) {
    f32x4 s_acc[2][2];
#pragma unroll
    for (int mi = 0; mi < 2; ++mi)
#pragma unroll
      for (int si = 0; si < 2; ++si)
#pragma unroll
        for (int r = 0; r < 4; ++r) s_acc[mi][si][r] = 0.f;

#pragma unroll
    for (int ks = 0; ks < 2; ++ks) {
      bf16x8 bk[2];
#pragma unroll
      for (int si = 0; si < 2; ++si) {
        const int srow = j * 32 + si * 16 + l15;
        const int kel = ks * 32 + lg * 8;
        bk[si] = *reinterpret_cast<const bf16x8*>(
            &Kls[srow * 64 + (kel ^ ((srow & 7) << 3))]);
      }
#pragma unroll
      for (int mi = 0; mi < 2; ++mi)
#pragma unroll
        for (int si = 0; si < 2; ++si)
          s_acc[mi][si] = __builtin_amdgcn_mfma_f32_16x16x32_bf16(
              a_q[mi][ks], bk[si], s_acc[mi][si], 0, 0, 0);
    }

    const bool diag = (j == qt);
#pragma unroll
    for (int mi = 0; mi < 2; ++mi) {
#pragma unroll
      for (int r = 0; r < 4; ++r) {
        const int mloc = mi * 16 + lg * 4 + r;
        float v0 = s_acc[mi][0][r] * 0.125f;
        float v1 = s_acc[mi][1][r] * 0.125f;
        if (diag) {
          if (l15 > mloc) v0 = -3.0e38f;
          if (16 + l15 > mloc) v1 = -3.0e38f;
        }
        float pm = fmaxf(v0, v1);
        pm = fmaxf(pm, __shfl_xor(pm, 1, 16));
        pm = fmaxf(pm, __shfl_xor(pm, 2, 16));
        pm = fmaxf(pm, __shfl_xor(pm, 4, 16));
        pm = fmaxf(pm, __shfl_xor(pm, 8, 16));
        const float mnew = fmaxf(mrun[mi][r], pm);
        const float alpha = __expf(mrun[mi][r] - mnew);
        mrun[mi][r] = mnew;
        const float p0 = __expf(v0 - mnew);
        const float p1 = __expf(v1 - mnew);
        float ps = p0 + p1;
        ps += __shfl_xor(ps, 1, 16);
        ps += __shfl_xor(ps, 2, 16);
        ps += __shfl_xor(ps, 4, 16);
        ps += __shfl_xor(ps, 8, 16);
        lrun[mi][r] = lrun[mi][r] * alpha + ps;
#pragma unroll
        for (int hi = 0; hi < 4; ++hi) o[mi][hi][r] *= alpha;
        Pls[w][mloc * 40 + l15] = f2bf(p0);
        Pls[w][mloc * 40 + 16 + l15] = f2bf(p1);
      }
    }

    bf16x8 pa[2];
#pragma unroll
    for (int mt = 0; mt < 2; ++mt)
      pa[mt] = *reinterpret_cast<const bf16x8*>(
          &Pls[w][(mt * 16 + l15) * 40 + lg * 8]);
#pragma unroll
    for (int hi = 0; hi < 4; ++hi) {
      const int h = hi * 16 + l15;
      const int sel = j * 32 + lg * 8;
      const bf16x8 bv = *reinterpret_cast<const bf16x8*>(
          &Vtls[h * 256 + (sel ^ ((h & 7) << 3))]);
#pragma unroll
      for (int mt = 0; mt < 2; ++mt)
        o[mt][hi] = __builtin_amdgcn_mfma_f32_16x16x32_bf16(
            pa[mt], bv, o[mt][hi], 0, 0, 0);
    }
  }

  float* og = out + ((size_t)b * NT + q0) * NH;
#pragma unroll
  for (int mi = 0; mi < 2; ++mi)
#pragma unroll
    for (int r = 0; r < 4; ++r) {
      const float inv = 1.f / lrun[mi][r];
      const int m = mi * 16 + lg * 4 + r;
#pragma unroll
      for (int hi = 0; hi < 4; ++hi)
        og[m * 64 + hi * 16 + l15] = o[mi][hi][r] * inv;
    }
}

// ---------------------------------------------------------------------------
extern "C" void kernel_launch(void* const* d_in, const int* in_sizes, int n_in,
                              void* d_out, int out_size, void* d_ws,
                              size_t ws_size, hipStream_t stream) {
  const float* x  = (const float*)d_in[0];
  const float* Wq = (const float*)d_in[1];
  const float* Wk = (const float*)d_in[2];
  const float* Wv = (const float*)d_in[3];
  unsigned short* Wt  = (unsigned short*)d_ws;            // 147 KB
  unsigned short* qkv = (unsigned short*)d_ws + WT_ELEMS; // 25.2 MB
  float* out = (float*)d_out;

  w_transpose_kernel<<<dim3((WT_ELEMS + 255) / 256), dim3(256), 0, stream>>>(
      Wq, Wk, Wv, Wt);
  qkv_proj_mfma<<<dim3(512), dim3(512), 0, stream>>>(x, Wt, qkv);
  attn_mfma_kernel<<<dim3(NB), dim3(512), 0, stream>>>(qkv, out);
}

// Round 7
// 46.731 us; speedup vs baseline: 1.8292x; 1.2266x over previous
//
#include <hip/hip_runtime.h>
#include <hip/hip_bf16.h>

// Problem constants (B, T, C, HS) from the reference.
#define NB 256
#define NT 256
#define NC 384
#define NH 64
#define NW 192              // 3 * NH concatenated output cols
#define WT_ELEMS (NW * NC)  // Wt bf16 elements = 73728

typedef short bf16x8 __attribute__((ext_vector_type(8)));
typedef float f32x4 __attribute__((ext_vector_type(4)));

__device__ __forceinline__ unsigned short f2bf(float f) {
  union { float f; unsigned int i; } c;
  c.f = f;
  const unsigned int r = c.i + 0x7fffu + ((c.i >> 16) & 1u);
  return (unsigned short)(r >> 16);
}

__device__ __forceinline__ unsigned short f2bf_hw(float f) {
  __hip_bfloat16 b = __float2bfloat16(f);
  return *reinterpret_cast<unsigned short*>(&b);
}

// ---------------------------------------------------------------------------
// Kernel 0: transpose + convert weights. Wt[n][k] bf16 [192][384].
// ---------------------------------------------------------------------------
__global__ __launch_bounds__(256) void w_transpose_kernel(
    const float* __restrict__ Wq,
    const float* __restrict__ Wk,
    const float* __restrict__ Wv,
    unsigned short* __restrict__ Wt) {
  const int idx = blockIdx.x * 256 + threadIdx.x;
  if (idx >= WT_ELEMS) return;
  const int n = idx / NC, k = idx - n * NC;
  const float* W = (n < 64) ? Wq : (n < 128) ? Wk : Wv;
  Wt[idx] = f2bf(W[k * NH + (n & 63)]);
}

// ---------------------------------------------------------------------------
// Kernel 1 (round 7): FUSED projection + causal flash attention.
// One block (512 thr = 8 waves) = one batch = one CU (LDS 116 KB -> 1/CU).
//
// Rounds 3-6 post-mortem: proj is stream-bound; the qkv HBM round-trip
// (write 25 MB + read 25 MB x2 streams) + 3 launches were ~40% of traffic.
// Fusion: wave w computes proj rows qt(w)*32..+32 x all 192 cols
// (acc[2][12]); its accumulators ARE its attention Q rows. K/V epilogue
// writes straight into the attention's swizzled LDS layouts. qkv never
// touches global memory.
//
// Proj: BK=32, 12 k-steps, x (2x32 KB fp32) and Wt (2x12 KB bf16) staged
// via contiguous global_load_lds (source-pre-swizzled so fragment
// ds_read_b128 are ~2-way/4-way spread).
// LDS time-share: X-bufs -> Kls+Vtls, W-bufs -> Qls(+8KB), fresh Pls.
// mfma_f32_16x16x32_bf16 layouts (HW-verified round 2):
//   A/B: k = (l>>4)*8+j contiguous;  D: n = l&15, m = (l>>4)*4 + r.
// ---------------------------------------------------------------------------
__global__ __launch_bounds__(512, 2) void fused_qkv_attn_kernel(
    const float* __restrict__ x,
    const unsigned short* __restrict__ Wt,
    float* __restrict__ out) {
  // Layout (bytes):
  //   [0,      65536)  X dbuf (2 x 32 KB fp32)   -> later Kls(32K)+Vtls(32K)
  //   [65536,  90112)  W dbuf (2 x 12 KB bf16)   -> later Qls (32 KB, +8K)
  //   [98304, 118784)  Pls [8][32*40] bf16 (20 KB)
  __shared__ __align__(16) unsigned char lds[118784];

  const int tid = threadIdx.x;
  const int w = tid >> 6;
  const int lane = tid & 63;
  const int l15 = lane & 15;
  const int lg = lane >> 4;
  const int b = blockIdx.x;
  const int row0 = b * NT;              // this block's 256 x-rows
  const int qt = (w < 4) ? w : 11 - w;  // causal-balanced q-tile per wave
  const int wbase = qt * 32;            // wave's 32 rows (block-local)

  // ---- proj phase ----
  f32x4 acc[2][12];
#pragma unroll
  for (int mi = 0; mi < 2; ++mi)
#pragma unroll
    for (int ni = 0; ni < 12; ++ni)
#pragma unroll
      for (int r = 0; r < 4; ++r) acc[mi][ni][r] = 0.f;

  // Stage 256x32 fp32 x-slice: 2048 16B chunks, 4/thread.
  // Physical chunk c of row holds logical chunk c^(row&7) (8 chunks/row).
#define STAGE_X(buf, kt)                                                      \
  {                                                                           \
    _Pragma("unroll") for (int j = 0; j < 4; ++j) {                           \
      const int idx = j * 512 + tid;                                          \
      const int srow = idx >> 3, c = idx & 7;                                 \
      const float* src = x + (size_t)(row0 + srow) * NC + (kt)*32 +           \
                         ((c ^ (srow & 7)) << 2);                             \
      __builtin_amdgcn_global_load_lds(                                       \
          (const __attribute__((address_space(1))) void*)src,                 \
          (__attribute__((address_space(3))) void*)(lds + (buf)*32768 +       \
                                                    idx * 16),                \
          16, 0, 0);                                                          \
    }                                                                         \
  }

  // Stage 192x32 bf16 W-slice: 768 16B chunks (4/row), waves 0-3 do j=1.
  // Physical chunk c holds logical chunk c^(row&3).
#define STAGE_W(buf, kt)                                                      \
  {                                                                           \
    _Pragma("unroll") for (int j = 0; j < 2; ++j) {                           \
      const int idx = j * 512 + tid;                                          \
      if (idx < 768) {                                                        \
        const int nrow = idx >> 2, c = idx & 3;                               \
        const unsigned short* src =                                           \
            Wt + (size_t)nrow * NC + (kt)*32 + ((c ^ (nrow & 3)) << 3);       \
        __builtin_amdgcn_global_load_lds(                                     \
            (const __attribute__((address_space(1))) void*)src,               \
            (__attribute__((address_space(3))) void*)(lds + 65536 +           \
                                                      (buf)*12288 + idx * 16),\
            16, 0, 0);                                                        \
      }                                                                       \
    }                                                                         \
  }

  STAGE_X(0, 0);
  STAGE_W(0, 0);
  __syncthreads();

  for (int kt = 0; kt < 12; ++kt) {
    const int cur = kt & 1;
    if (kt < 11) {
      STAGE_X(cur ^ 1, kt + 1);
      STAGE_W(cur ^ 1, kt + 1);
    }

    const float* Xc = reinterpret_cast<const float*>(lds + cur * 32768);
    const unsigned short* Wc =
        reinterpret_cast<const unsigned short*>(lds + 65536 + cur * 12288);

    // A fragments (fp32 -> bf16). Logical chunks 2lg, 2lg+1 of this row.
    bf16x8 afr[2];
#pragma unroll
    for (int mi = 0; mi < 2; ++mi) {
      const int rl = wbase + mi * 16 + l15;
      const int s0 = (lg * 2) ^ (rl & 7);
      const int s1 = (lg * 2 + 1) ^ (rl & 7);
      const float4 lo = *reinterpret_cast<const float4*>(Xc + rl * 32 + s0 * 4);
      const float4 hi = *reinterpret_cast<const float4*>(Xc + rl * 32 + s1 * 4);
      union { bf16x8 v; unsigned short u[8]; } au;
      au.u[0] = f2bf_hw(lo.x);
      au.u[1] = f2bf_hw(lo.y);
      au.u[2] = f2bf_hw(lo.z);
      au.u[3] = f2bf_hw(lo.w);
      au.u[4] = f2bf_hw(hi.x);
      au.u[5] = f2bf_hw(hi.y);
      au.u[6] = f2bf_hw(hi.z);
      au.u[7] = f2bf_hw(hi.w);
      afr[mi] = au.v;
    }
    // B fragments + MFMA over all 12 col-tiles.
#pragma unroll
    for (int ni = 0; ni < 12; ++ni) {
      const int n = ni * 16 + l15;
      const int ch = lg ^ (n & 3);
      const bf16x8 bfr =
          *reinterpret_cast<const bf16x8*>(Wc + n * 32 + ch * 8);
      acc[0][ni] = __builtin_amdgcn_mfma_f32_16x16x32_bf16(
          afr[0], bfr, acc[0][ni], 0, 0, 0);
      acc[1][ni] = __builtin_amdgcn_mfma_f32_16x16x32_bf16(
          afr[1], bfr, acc[1][ni], 0, 0, 0);
    }
    __syncthreads();
  }

  // ---- epilogue: scatter acc into attention LDS layouts (bf16) ----
  unsigned short* Kls = reinterpret_cast<unsigned short*>(lds);           // 32K
  unsigned short* Vtls = reinterpret_cast<unsigned short*>(lds + 32768);  // 32K
  unsigned short* Qls = reinterpret_cast<unsigned short*>(lds + 65536);   // 32K
  unsigned short* Pls = reinterpret_cast<unsigned short*>(lds + 98304);   // 20K

#pragma unroll
  for (int mi = 0; mi < 2; ++mi)
#pragma unroll
    for (int ni = 0; ni < 12; ++ni) {
      const int n = ni * 16 + l15;
#pragma unroll
      for (int r = 0; r < 4; ++r) {
        const int srow = wbase + mi * 16 + lg * 4 + r;
        const unsigned short val = f2bf_hw(acc[mi][ni][r]);
        if (ni < 4) {
          Qls[srow * 64 + (n ^ ((srow & 7) << 3))] = val;
        } else if (ni < 8) {
          const int h = n - 64;
          Kls[srow * 64 + (h ^ ((srow & 7) << 3))] = val;
        } else {
          const int h = n - 128;
          Vtls[h * 256 + (srow ^ ((h & 7) << 3))] = val;
        }
      }
    }
  __syncthreads();

  // ---- attention phase (flash, per-wave independent) ----
  const int q0 = wbase;
  bf16x8 a_q[2][2];
#pragma unroll
  for (int mi = 0; mi < 2; ++mi)
#pragma unroll
    for (int ks = 0; ks < 2; ++ks) {
      const int srow = q0 + mi * 16 + l15;
      a_q[mi][ks] = *reinterpret_cast<const bf16x8*>(
          Qls + srow * 64 + ((ks * 32 + lg * 8) ^ ((srow & 7) << 3)));
    }

  f32x4 o[2][4];
  float mrun[2][4], lrun[2][4];
#pragma unroll
  for (int mi = 0; mi < 2; ++mi)
#pragma unroll
    for (int r = 0; r < 4; ++r) {
      mrun[mi][r] = -3.0e38f;
      lrun[mi][r] = 0.f;
#pragma unroll
      for (int hi = 0; hi < 4; ++hi) o[mi][hi][r] = 0.f;
    }

  unsigned short* Pw = Pls + w * 1280;  // per-wave [32][40]

  for (int j = 0; j <= qt; ++j) {
    f32x4 s_acc[2][2];
#pragma unroll
    for (int mi = 0; mi < 2; ++mi)
#pragma unroll
      for (int si = 0; si < 2; ++si)
#pragma unroll
        for (int r = 0; r < 4; ++r) s_acc[mi][si][r] = 0.f;

#pragma unroll
    for (int ks = 0; ks < 2; ++ks) {
      bf16x8 bk[2];
#pragma unroll
      for (int si = 0; si < 2; ++si) {
        const int srow = j * 32 + si * 16 + l15;
        const int kel = ks * 32 + lg * 8;
        bk[si] = *reinterpret_cast<const bf16x8*>(
            Kls + srow * 64 + (kel ^ ((srow & 7) << 3)));
      }
#pragma unroll
      for (int mi = 0; mi < 2; ++mi)
#pragma unroll
        for (int si = 0; si < 2; ++si)
          s_acc[mi][si] = __builtin_amdgcn_mfma_f32_16x16x32_bf16(
              a_q[mi][ks], bk[si], s_acc[mi][si], 0, 0, 0);
    }

    const bool diag = (j == qt);
#pragma unroll
    for (int mi = 0; mi < 2; ++mi) {
#pragma unroll
      for (int r = 0; r < 4; ++r) {
        const int mloc = mi * 16 + lg * 4 + r;
        float v0 = s_acc[mi][0][r] * 0.125f;
        float v1 = s_acc[mi][1][r] * 0.125f;
        if (diag) {
          if (l15 > mloc) v0 = -3.0e38f;
          if (16 + l15 > mloc) v1 = -3.0e38f;
        }
        float pm = fmaxf(v0, v1);
        pm = fmaxf(pm, __shfl_xor(pm, 1, 16));
        pm = fmaxf(pm, __shfl_xor(pm, 2, 16));
        pm = fmaxf(pm, __shfl_xor(pm, 4, 16));
        pm = fmaxf(pm, __shfl_xor(pm, 8, 16));
        const float mnew = fmaxf(mrun[mi][r], pm);
        const float alpha = __expf(mrun[mi][r] - mnew);
        mrun[mi][r] = mnew;
        const float p0 = __expf(v0 - mnew);
        const float p1 = __expf(v1 - mnew);
        float ps = p0 + p1;
        ps += __shfl_xor(ps, 1, 16);
        ps += __shfl_xor(ps, 2, 16);
        ps += __shfl_xor(ps, 4, 16);
        ps += __shfl_xor(ps, 8, 16);
        lrun[mi][r] = lrun[mi][r] * alpha + ps;
#pragma unroll
        for (int hi = 0; hi < 4; ++hi) o[mi][hi][r] *= alpha;
        Pw[mloc * 40 + l15] = f2bf(p0);
        Pw[mloc * 40 + 16 + l15] = f2bf(p1);
      }
    }

    bf16x8 pa[2];
#pragma unroll
    for (int mt = 0; mt < 2; ++mt)
      pa[mt] = *reinterpret_cast<const bf16x8*>(
          Pw + (mt * 16 + l15) * 40 + lg * 8);
#pragma unroll
    for (int hi = 0; hi < 4; ++hi) {
      const int h = hi * 16 + l15;
      const int sel = j * 32 + lg * 8;
      const bf16x8 bv = *reinterpret_cast<const bf16x8*>(
          Vtls + h * 256 + (sel ^ ((h & 7) << 3)));
#pragma unroll
      for (int mt = 0; mt < 2; ++mt)
        o[mt][hi] = __builtin_amdgcn_mfma_f32_16x16x32_bf16(
            pa[mt], bv, o[mt][hi], 0, 0, 0);
    }
  }

  // ---- out store ----
  float* og = out + ((size_t)b * NT + q0) * NH;
#pragma unroll
  for (int mi = 0; mi < 2; ++mi)
#pragma unroll
    for (int r = 0; r < 4; ++r) {
      const float inv = 1.f / lrun[mi][r];
      const int m = mi * 16 + lg * 4 + r;
#pragma unroll
      for (int hi = 0; hi < 4; ++hi)
        og[m * 64 + hi * 16 + l15] = o[mi][hi][r] * inv;
    }
}

// ---------------------------------------------------------------------------
extern "C" void kernel_launch(void* const* d_in, const int* in_sizes, int n_in,
                              void* d_out, int out_size, void* d_ws,
                              size_t ws_size, hipStream_t stream) {
  const float* x  = (const float*)d_in[0];
  const float* Wq = (const float*)d_in[1];
  const float* Wk = (const float*)d_in[2];
  const float* Wv = (const float*)d_in[3];
  unsigned short* Wt = (unsigned short*)d_ws;  // 147 KB
  float* out = (float*)d_out;

  w_transpose_kernel<<<dim3((WT_ELEMS + 255) / 256), dim3(256), 0, stream>>>(
      Wq, Wk, Wv, Wt);
  fused_qkv_attn_kernel<<<dim3(NB), dim3(512), 0, stream>>>(x, Wt, out);
}

// Round 9
// 42.814 us; speedup vs baseline: 1.9965x; 1.0915x over previous
//
#include <hip/hip_runtime.h>
#include <hip/hip_bf16.h>

// Problem constants (B, T, C, HS) from the reference.
#define NB 256
#define NT 256
#define NC 384
#define NH 64
#define NW 192              // 3 * NH concatenated output cols
#define WT_ELEMS (NW * NC)  // Wt bf16 elements = 73728

typedef short bf16x8 __attribute__((ext_vector_type(8)));
typedef float f32x4 __attribute__((ext_vector_type(4)));

__device__ __forceinline__ unsigned short f2bf(float f) {
  union { float f; unsigned int i; } c;
  c.f = f;
  const unsigned int r = c.i + 0x7fffu + ((c.i >> 16) & 1u);
  return (unsigned short)(r >> 16);
}

__device__ __forceinline__ unsigned short f2bf_hw(float f) {
  __hip_bfloat16 b = __float2bfloat16(f);
  return *reinterpret_cast<unsigned short*>(&b);
}

// ---------------------------------------------------------------------------
// Kernel 0: transpose + convert weights. Wt[n][k] bf16 [192][384].
// ---------------------------------------------------------------------------
__global__ __launch_bounds__(256) void w_transpose_kernel(
    const float* __restrict__ Wq,
    const float* __restrict__ Wk,
    const float* __restrict__ Wv,
    unsigned short* __restrict__ Wt) {
  const int idx = blockIdx.x * 256 + threadIdx.x;
  if (idx >= WT_ELEMS) return;
  const int n = idx / NC, k = idx - n * NC;
  const float* W = (n < 64) ? Wq : (n < 128) ? Wk : Wv;
  Wt[idx] = f2bf(W[k * NH + (n & 63)]);
}

// ---------------------------------------------------------------------------
// Kernel 1 (round 9): fused proj+attn, counted-vmcnt 3-deep pipeline.
//
// Round-8 post-mortem: crash was an OOB prefetch — the loop staged tile
// t+3 unconditionally, so t=9 staged nonexistent tile 12, reading up to
// 416 B past the end of x (whose size is exactly page-aligned) -> unmapped
// page -> abort. Fix: guard stage to t<9 (tiles 3..11 only); drain ledger
// becomes exact (12 outstanding after loop: vmcnt(6) retires tile 10,
// vmcnt(0) retires tile 11). Also add explicit lgkmcnt(0) before the
// post-compute barrier (rule-18 hardening: no wave crosses the barrier
// with pending ds_reads of the buffer others will overwrite).
//
// Pipeline ledger (6 vmem ops/thread per STAGE, wave-uniform):
//   prologue: stage 0,1,2 -> 18 outstanding
//   t=0..9:  vmcnt(12) retires tile t; barrier; COMPUTE(t%3);
//            lgkmcnt(0); barrier; if t<9 STAGE(t%3, t+3)
//   epilogue: vmcnt(6) retires tile 10; COMPUTE(1); vmcnt(0); COMPUTE(2)
//
// LDS map (135168 B total, 1 block/CU):
//   [0,      98304)  X bufs 3 x 32 KB (256x32 fp32 k-slice, src-swizzled)
//                    -> attn: Kls(32K) | Vtls(32K) | Qls(32K)
//   [98304, 135168)  W bufs 3 x 12 KB (192x32 bf16 k-slice, src-swizzled)
//                    -> attn: Pls 8 x [32][40] bf16 (20 KB)
// mfma_f32_16x16x32_bf16 layouts (HW-verified round 2):
//   A/B: k = (l>>4)*8+j contiguous;  D: n = l&15, m = (l>>4)*4 + r.
// ---------------------------------------------------------------------------
#define XB 32768
#define WB 12288
#define XTOT 98304
__global__ __launch_bounds__(512, 2) void fused_qkv_attn_kernel(
    const float* __restrict__ x,
    const unsigned short* __restrict__ Wt,
    float* __restrict__ out) {
  __shared__ __align__(16) unsigned char lds[XTOT + 3 * WB];  // 132 KB

  const int tid = threadIdx.x;
  const int w = tid >> 6;
  const int lane = tid & 63;
  const int l15 = lane & 15;
  const int lg = lane >> 4;
  const int b = blockIdx.x;
  const int row0 = b * NT;              // this block's 256 x-rows
  const int qt = (w < 4) ? w : 11 - w;  // causal-balanced q-tile per wave
  const int wbase = qt * 32;            // wave's 32 rows (block-local)

  f32x4 acc[2][12];
#pragma unroll
  for (int mi = 0; mi < 2; ++mi)
#pragma unroll
    for (int ni = 0; ni < 12; ++ni)
#pragma unroll
      for (int r = 0; r < 4; ++r) acc[mi][ni][r] = 0.f;

  // Stage tile kt into buffer buf: 4 X-chunks + 2 W-chunks per thread
  // (wave-uniform 6 vmem ops). Source-pre-swizzled: X phys chunk c holds
  // logical c^(srow&7); W phys chunk c holds logical c^(nrow&3). W's
  // chunks 512..767 are written twice (same src, same dst - benign).
#define STAGE(buf, kt)                                                        \
  {                                                                           \
    _Pragma("unroll") for (int j = 0; j < 4; ++j) {                           \
      const int idx = j * 512 + tid;                                          \
      const int srow = idx >> 3, c = idx & 7;                                 \
      const float* src = x + (size_t)(row0 + srow) * NC + (kt)*32 +           \
                         ((c ^ (srow & 7)) << 2);                             \
      __builtin_amdgcn_global_load_lds(                                       \
          (const __attribute__((address_space(1))) void*)src,                 \
          (__attribute__((address_space(3))) void*)(lds + (buf)*XB +          \
                                                    idx * 16),                \
          16, 0, 0);                                                          \
    }                                                                         \
    _Pragma("unroll") for (int j = 0; j < 2; ++j) {                           \
      const int raw = j * 512 + tid;                                          \
      const int idx = (raw < 768) ? raw : raw - 256;                          \
      const int nrow = idx >> 2, c = idx & 3;                                 \
      const unsigned short* src =                                             \
          Wt + (size_t)nrow * NC + (kt)*32 + ((c ^ (nrow & 3)) << 3);         \
      __builtin_amdgcn_global_load_lds(                                       \
          (const __attribute__((address_space(1))) void*)src,                 \
          (__attribute__((address_space(3))) void*)(lds + XTOT + (buf)*WB +   \
                                                    idx * 16),                \
          16, 0, 0);                                                          \
    }                                                                         \
  }

  // Compute one k-step from buffer buf.
#define COMPUTE(buf)                                                          \
  {                                                                           \
    const float* Xc = reinterpret_cast<const float*>(lds + (buf)*XB);         \
    const unsigned short* Wc =                                                \
        reinterpret_cast<const unsigned short*>(lds + XTOT + (buf)*WB);       \
    bf16x8 afr[2];                                                            \
    _Pragma("unroll") for (int mi = 0; mi < 2; ++mi) {                        \
      const int rl = wbase + mi * 16 + l15;                                   \
      const int s0 = (lg * 2) ^ (rl & 7);                                     \
      const int s1 = (lg * 2 + 1) ^ (rl & 7);                                 \
      const float4 lo =                                                       \
          *reinterpret_cast<const float4*>(Xc + rl * 32 + s0 * 4);            \
      const float4 hi =                                                       \
          *reinterpret_cast<const float4*>(Xc + rl * 32 + s1 * 4);            \
      union { bf16x8 v; unsigned short u[8]; } au;                            \
      au.u[0] = f2bf_hw(lo.x); au.u[1] = f2bf_hw(lo.y);                       \
      au.u[2] = f2bf_hw(lo.z); au.u[3] = f2bf_hw(lo.w);                       \
      au.u[4] = f2bf_hw(hi.x); au.u[5] = f2bf_hw(hi.y);                       \
      au.u[6] = f2bf_hw(hi.z); au.u[7] = f2bf_hw(hi.w);                       \
      afr[mi] = au.v;                                                         \
    }                                                                         \
    _Pragma("unroll") for (int ni = 0; ni < 12; ++ni) {                       \
      const int n = ni * 16 + l15;                                            \
      const int ch = lg ^ (n & 3);                                            \
      const bf16x8 bfr =                                                      \
          *reinterpret_cast<const bf16x8*>(Wc + n * 32 + ch * 8);             \
      acc[0][ni] = __builtin_amdgcn_mfma_f32_16x16x32_bf16(                   \
          afr[0], bfr, acc[0][ni], 0, 0, 0);                                  \
      acc[1][ni] = __builtin_amdgcn_mfma_f32_16x16x32_bf16(                   \
          afr[1], bfr, acc[1][ni], 0, 0, 0);                                  \
    }                                                                         \
  }

  // ---- proj pipeline: 3-deep, counted vmcnt (never 0 in steady state) ----
  STAGE(0, 0);
  STAGE(1, 1);
  STAGE(2, 2);

  int bufc = 0;
  for (int t = 0; t < 10; ++t) {
    // tiles t+1, t+2 in flight = 12 vmem ops/wave; wait until tile t done.
    asm volatile("s_waitcnt vmcnt(12)" ::: "memory");
    __builtin_amdgcn_s_barrier();
    COMPUTE(bufc);
    asm volatile("s_waitcnt lgkmcnt(0)" ::: "memory");
    __builtin_amdgcn_s_barrier();  // all waves done reading bufc
    if (t < 9) STAGE(bufc, t + 3);  // tiles 3..11 only (12 exists NOT)
    bufc = (bufc == 2) ? 0 : bufc + 1;
  }
  // Outstanding now: tiles 10, 11 (12 ops). Retire tile 10.
  asm volatile("s_waitcnt vmcnt(6)" ::: "memory");
  __builtin_amdgcn_s_barrier();
  COMPUTE(1);
  // Drain tile 11.
  asm volatile("s_waitcnt vmcnt(0)" ::: "memory");
  __builtin_amdgcn_s_barrier();
  COMPUTE(2);

  __syncthreads();

  // ---- epilogue: scatter acc into attention LDS layouts (bf16) ----
  unsigned short* Kls = reinterpret_cast<unsigned short*>(lds);           // 32K
  unsigned short* Vtls = reinterpret_cast<unsigned short*>(lds + 32768);  // 32K
  unsigned short* Qls = reinterpret_cast<unsigned short*>(lds + 65536);   // 32K
  unsigned short* Pls = reinterpret_cast<unsigned short*>(lds + XTOT);    // 20K

#pragma unroll
  for (int mi = 0; mi < 2; ++mi)
#pragma unroll
    for (int ni = 0; ni < 12; ++ni) {
      const int n = ni * 16 + l15;
#pragma unroll
      for (int r = 0; r < 4; ++r) {
        const int srow = wbase + mi * 16 + lg * 4 + r;
        const unsigned short val = f2bf_hw(acc[mi][ni][r]);
        if (ni < 4) {
          Qls[srow * 64 + (n ^ ((srow & 7) << 3))] = val;
        } else if (ni < 8) {
          const int h = n - 64;
          Kls[srow * 64 + (h ^ ((srow & 7) << 3))] = val;
        } else {
          const int h = n - 128;
          Vtls[h * 256 + (srow ^ ((h & 7) << 3))] = val;
        }
      }
    }
  __syncthreads();

  // ---- attention phase (flash, per-wave independent) ----
  const int q0 = wbase;
  bf16x8 a_q[2][2];
#pragma unroll
  for (int mi = 0; mi < 2; ++mi)
#pragma unroll
    for (int ks = 0; ks < 2; ++ks) {
      const int srow = q0 + mi * 16 + l15;
      a_q[mi][ks] = *reinterpret_cast<const bf16x8*>(
          Qls + srow * 64 + ((ks * 32 + lg * 8) ^ ((srow & 7) << 3)));
    }

  f32x4 o[2][4];
  float mrun[2][4], lrun[2][4];
#pragma unroll
  for (int mi = 0; mi < 2; ++mi)
#pragma unroll
    for (int r = 0; r < 4; ++r) {
      mrun[mi][r] = -3.0e38f;
      lrun[mi][r] = 0.f;
#pragma unroll
      for (int hi = 0; hi < 4; ++hi) o[mi][hi][r] = 0.f;
    }

  unsigned short* Pw = Pls + w * 1280;  // per-wave [32][40]

  for (int j = 0; j <= qt; ++j) {
    f32x4 s_acc[2][2];
#pragma unroll
    for (int mi = 0; mi < 2; ++mi)
#pragma unroll
      for (int si = 0; si < 2; ++si)
#pragma unroll
        for (int r = 0; r < 4; ++r) s_acc[mi][si][r] = 0.f;

#pragma unroll
    for (int ks = 0; ks < 2; ++ks) {
      bf16x8 bk[2];
#pragma unroll
      for (int si = 0; si < 2; ++si) {
        const int srow = j * 32 + si * 16 + l15;
        const int kel = ks * 32 + lg * 8;
        bk[si] = *reinterpret_cast<const bf16x8*>(
            Kls + srow * 64 + (kel ^ ((srow & 7) << 3)));
      }
#pragma unroll
      for (int mi = 0; mi < 2; ++mi)
#pragma unroll
        for (int si = 0; si < 2; ++si)
          s_acc[mi][si] = __builtin_amdgcn_mfma_f32_16x16x32_bf16(
              a_q[mi][ks], bk[si], s_acc[mi][si], 0, 0, 0);
    }

    const bool diag = (j == qt);
#pragma unroll
    for (int mi = 0; mi < 2; ++mi) {
#pragma unroll
      for (int r = 0; r < 4; ++r) {
        const int mloc = mi * 16 + lg * 4 + r;
        float v0 = s_acc[mi][0][r] * 0.125f;
        float v1 = s_acc[mi][1][r] * 0.125f;
        if (diag) {
          if (l15 > mloc) v0 = -3.0e38f;
          if (16 + l15 > mloc) v1 = -3.0e38f;
        }
        float pm = fmaxf(v0, v1);
        pm = fmaxf(pm, __shfl_xor(pm, 1, 16));
        pm = fmaxf(pm, __shfl_xor(pm, 2, 16));
        pm = fmaxf(pm, __shfl_xor(pm, 4, 16));
        pm = fmaxf(pm, __shfl_xor(pm, 8, 16));
        const float mnew = fmaxf(mrun[mi][r], pm);
        const float alpha = __expf(mrun[mi][r] - mnew);
        mrun[mi][r] = mnew;
        const float p0 = __expf(v0 - mnew);
        const float p1 = __expf(v1 - mnew);
        float ps = p0 + p1;
        ps += __shfl_xor(ps, 1, 16);
        ps += __shfl_xor(ps, 2, 16);
        ps += __shfl_xor(ps, 4, 16);
        ps += __shfl_xor(ps, 8, 16);
        lrun[mi][r] = lrun[mi][r] * alpha + ps;
#pragma unroll
        for (int hi = 0; hi < 4; ++hi) o[mi][hi][r] *= alpha;
        Pw[mloc * 40 + l15] = f2bf(p0);
        Pw[mloc * 40 + 16 + l15] = f2bf(p1);
      }
    }

    bf16x8 pa[2];
#pragma unroll
    for (int mt = 0; mt < 2; ++mt)
      pa[mt] = *reinterpret_cast<const bf16x8*>(
          Pw + (mt * 16 + l15) * 40 + lg * 8);
#pragma unroll
    for (int hi = 0; hi < 4; ++hi) {
      const int h = hi * 16 + l15;
      const int sel = j * 32 + lg * 8;
      const bf16x8 bv = *reinterpret_cast<const bf16x8*>(
          Vtls + h * 256 + (sel ^ ((h & 7) << 3)));
#pragma unroll
      for (int mt = 0; mt < 2; ++mt)
        o[mt][hi] = __builtin_amdgcn_mfma_f32_16x16x32_bf16(
            pa[mt], bv, o[mt][hi], 0, 0, 0);
    }
  }

  // ---- out store ----
  float* og = out + ((size_t)b * NT + q0) * NH;
#pragma unroll
  for (int mi = 0; mi < 2; ++mi)
#pragma unroll
    for (int r = 0; r < 4; ++r) {
      const float inv = 1.f / lrun[mi][r];
      const int m = mi * 16 + lg * 4 + r;
#pragma unroll
      for (int hi = 0; hi < 4; ++hi)
        og[m * 64 + hi * 16 + l15] = o[mi][hi][r] * inv;
    }
}

// ---------------------------------------------------------------------------
extern "C" void kernel_launch(void* const* d_in, const int* in_sizes, int n_in,
                              void* d_out, int out_size, void* d_ws,
                              size_t ws_size, hipStream_t stream) {
  const float* x  = (const float*)d_in[0];
  const float* Wq = (const float*)d_in[1];
  const float* Wk = (const float*)d_in[2];
  const float* Wv = (const float*)d_in[3];
  unsigned short* Wt = (unsigned short*)d_ws;  // 147 KB
  float* out = (float*)d_out;

  w_transpose_kernel<<<dim3((WT_ELEMS + 255) / 256), dim3(256), 0, stream>>>(
      Wq, Wk, Wv, Wt);
  fused_qkv_attn_kernel<<<dim3(NB), dim3(512), 0, stream>>>(x, Wt, out);
}